// Round 11
// baseline (200.941 us; speedup 1.0000x reference)
//
#include <hip/hip_runtime.h>
#include <hip/hip_bf16.h>

#define B_ 8
#define C_ 64
#define H_ 128
#define W_ 128
#define HW_  ((size_t)H_ * W_)          // 16384
#define CHW_ ((size_t)C_ * H_ * W_)     // 1048576

typedef unsigned short u16;
typedef unsigned int   u32;
typedef __attribute__((ext_vector_type(8))) short bf16x8;
typedef __attribute__((ext_vector_type(4))) float f32x4;

__device__ __forceinline__ float bf2f(u16 h) {
    union { u32 u; float f; } c; c.u = ((u32)h) << 16; return c.f;
}
__device__ __forceinline__ u16 f2bf(float f) {
    union { float f; u32 u; } c; c.f = f;
    u32 u = c.u;
    u32 r = (u + 0x7fffu + ((u >> 16) & 1u)) >> 16;
    return (u16)r;
}
__device__ __forceinline__ u32 pack2(float a, float b) {
    return (u32)f2bf(a) | ((u32)f2bf(b) << 16);
}
__device__ __forceinline__ float sanit(float x, float lo, float hi) {
    return fminf(fmaxf(x, lo), hi);   // NaN-killing clamp
}
// async global->LDS, 16B per lane, LDS dest = uniform base + lane*16
__device__ __forceinline__ void gload_lds16(const u16* g, u16* l) {
    __builtin_amdgcn_global_load_lds(
        (const __attribute__((address_space(1))) void*)g,
        (__attribute__((address_space(3))) void*)l, 16, 0, 0);
}

// ---------------------------------------------------------------------------
// Weight prep: Wt[tap][cog(192)][ci(64)] bf16, cog = {q:0..63, k:64..127, v:128..191}
// ---------------------------------------------------------------------------
__global__ __launch_bounds__(256) void prep_weights(
    const float* __restrict__ Wq, const float* __restrict__ Wk,
    const float* __restrict__ Wv, u16* __restrict__ Wt)
{
    int tap = blockIdx.x;
    int cog = blockIdx.y * 4 + (threadIdx.x >> 6);
    int ci  = threadIdx.x & 63;
    int arr = cog >> 6, co = cog & 63;
    const float* src = arr == 0 ? Wq : (arr == 1 ? Wk : Wv);
    Wt[tap * 12288 + cog * 64 + ci] = f2bf(src[(co * 64 + ci) * 9 + tap]);
}

// ---------------------------------------------------------------------------
// x prep: fp32 NCHW -> bf16 [b][h'(130)][g(8)][px(128)][8ch], rows h'=0 and
// h'=129 zeroed (h-halo). One thread builds one 16B unit (8 ch of one px).
// grid (130, nb), 256 thr.
// ---------------------------------------------------------------------------
__global__ __launch_bounds__(256) void xprep_kernel(
    const float* __restrict__ x, u16* __restrict__ xb)
{
    const int hp  = blockIdx.x;            // 0..129
    const int tid = threadIdx.x;
    u16* dst = xb + ((size_t)blockIdx.y * 130 + hp) * 8192;
    if (hp == 0 || hp == 129) {
#pragma unroll
        for (int i = 0; i < 4; i++)
            *(uint4*)(dst + (size_t)(tid + i * 256) * 8) = (uint4){0, 0, 0, 0};
        return;
    }
    const float* xr = x + (size_t)blockIdx.y * CHW_ + (size_t)(hp - 1) * W_;
#pragma unroll
    for (int it = 0; it < 4; it++) {
        int idx = tid + it * 256;          // 0..1023
        int px  = idx & 127;
        int g   = idx >> 7;                // 0..7
        float vb[8];
#pragma unroll
        for (int e = 0; e < 8; e++)
            vb[e] = xr[(size_t)(g * 8 + e) * HW_ + px];
        uint4 o;
        o.x = pack2(vb[0], vb[1]);
        o.y = pack2(vb[2], vb[3]);
        o.z = pack2(vb[4], vb[5]);
        o.w = pack2(vb[6], vb[7]);
        *(uint4*)(dst + (size_t)(g * 128 + px) * 8) = o;
    }
}

// ---------------------------------------------------------------------------
// Conv implicit-GEMM MFMA, 4-row/half-px blocks + FUSED vT write.
// grid (64, nb). Swizzle: XCD = blockIdx%8 = p*4+hq_hi, so the 8 hq-siblings
// of each (b,p,hq_hi) group share an XCD: their 8B vT[c][w][h0..3] partial-
// sector writes merge in that XCD's L2 (all 512 blocks co-resident at 2/CU),
// and h-halo neighbors share the L2 too. Pass-0 v accs held in 32 regs; one
// uint2 (4 h) store per (c,px) after pass 1. vt_kernel eliminated.
// LDS: xI[6 row][8 g][68 px][8 ch] = 52224 B.
// ---------------------------------------------------------------------------
__global__ __launch_bounds__(256, 2) void conv_mfma_kernel(
    const u16* __restrict__ xb, const u16* __restrict__ Wt,
    const float* __restrict__ bq, const float* __restrict__ bk,
    const float* __restrict__ bv,
    u16* __restrict__ qN, u16* __restrict__ kN,
    u16* __restrict__ v, u16* __restrict__ vT)
{
    // group/member decode: F = m*groups + g; XCD(F) = F&7 = g&7 = p*4+hq_hi
    const int nwg    = gridDim.x * gridDim.y;      // 64*nb
    const int flat   = blockIdx.y * gridDim.x + blockIdx.x;
    const int groups = nwg >> 3;                   // 8*nb (mult of 8 for nb>=1)
    const int m      = flat / groups;              // 0..7  = hq low bits
    const int g      = flat - m * groups;          // 0..groups-1
    const int bidx   = g >> 3;
    const int p      = (g >> 2) & 1;               // px half
    const int hq     = (g & 3) * 8 + m;            // 0..31
    const int h0     = hq * 4;
    const size_t boff = (size_t)bidx * CHW_;
    const int tid  = threadIdx.x;
    const int lane = tid & 63, wv = tid >> 6;
    const int ln15 = lane & 15, quad = lane >> 4;

    __shared__ __align__(16) u16 xI[26112];    // 52224 B

    // per-lane weight-fragment offset: + mt*4096 + ks*32 + tap*12288
    const int woff = (wv * 16 + ln15) * 64 + quad * 8;

    // stage 6 rows x 8 g, 1088 B each as two overlapping full-wave 1KB chunks
    const u16* xrow0 = xb + ((size_t)bidx * 130 + h0) * 8192;  // xb row h0+i
#pragma unroll
    for (int it = 0; it < 12; it++) {
        int unit = wv * 12 + it;               // 0..47
        int i = unit >> 3, gg = unit & 7;
        const u16* src = xrow0 + (size_t)i * 8192 + gg * 1024 + p * 512 - 16;
        u16* dst = xI + (i * 8 + gg) * 544;
        gload_lds16(src + lane * 8, dst);           // bytes [0,1024)
        gload_lds16(src + 32 + lane * 8, dst + 32); // bytes [64,1088)
    }
    __syncthreads();
    // zero the w-boundary column: global px -1 (p=0) / 128 (p=1)
    if (tid < 48) {
        int i = tid >> 3, gg = tid & 7;
        int slot = p ? 66 : 1;
        *(uint4*)(xI + (i * 8 + gg) * 544 + slot * 8) = (uint4){0, 0, 0, 0};
    }
    __syncthreads();

    const int cb = wv * 16 + quad * 4;
    float bqv[4], bkv[4], bvv[4];
#pragma unroll
    for (int r = 0; r < 4; r++) {
        bqv[r] = bq[cb + r]; bkv[r] = bk[cb + r]; bvv[r] = bv[cb + r];
    }

    float vhold[2][4][4];                      // pass-0 biased v values

#pragma unroll
    for (int pass = 0; pass < 2; pass++) {
        f32x4 acc[2][3][4];
#pragma unroll
        for (int hh = 0; hh < 2; hh++)
#pragma unroll
            for (int mt = 0; mt < 3; mt++)
#pragma unroll
                for (int nt = 0; nt < 4; nt++)
                    acc[hh][mt][nt] = (f32x4){0.f, 0.f, 0.f, 0.f};

        bf16x8 wcur[2][3], wnxt[2][3];
#pragma unroll
        for (int ks = 0; ks < 2; ks++)
#pragma unroll
            for (int mt = 0; mt < 3; mt++)
                wcur[ks][mt] = *(const bf16x8*)(Wt + woff + mt * 4096 + ks * 32);

#pragma unroll
        for (int tap = 0; tap < 9; tap++) {
            const int dh = tap / 3, dw = tap % 3;
            if (tap < 8) {
#pragma unroll
                for (int ks = 0; ks < 2; ks++)
#pragma unroll
                    for (int mt = 0; mt < 3; mt++)
                        wnxt[ks][mt] = *(const bf16x8*)(Wt + (tap + 1) * 12288 + woff + mt * 4096 + ks * 32);
            }
#pragma unroll
            for (int hh = 0; hh < 2; hh++) {
                const int row = pass * 2 + hh + dh;      // 0..5
#pragma unroll
                for (int ks = 0; ks < 2; ks++) {
                    bf16x8 bfr[4];
#pragma unroll
                    for (int nt = 0; nt < 4; nt++)
                        bfr[nt] = *(const bf16x8*)(xI + (row * 8 + quad + ks * 4) * 544
                                                      + (nt * 16 + ln15 + 1 + dw) * 8);
                    __builtin_amdgcn_s_setprio(1);
#pragma unroll
                    for (int mt = 0; mt < 3; mt++)
#pragma unroll
                        for (int nt = 0; nt < 4; nt++)
                            acc[hh][mt][nt] = __builtin_amdgcn_mfma_f32_16x16x32_bf16(
                                wcur[ks][mt], bfr[nt], acc[hh][mt][nt], 0, 0, 0);
                    __builtin_amdgcn_s_setprio(0);
                }
            }
            if (tap < 8) {
#pragma unroll
                for (int ks = 0; ks < 2; ks++)
#pragma unroll
                    for (int mt = 0; mt < 3; mt++)
                        wcur[ks][mt] = wnxt[ks][mt];
            }
        }

        // epilogue for this pass's two rows
#pragma unroll
        for (int hh = 0; hh < 2; hh++) {
            const int h = h0 + pass * 2 + hh;
            // q/k: NHWC packed u32 direct
#pragma unroll
            for (int mt = 0; mt < 2; mt++) {
                const float* bb = mt == 0 ? bqv : bkv;
                u16* dst = (mt ? kN : qN) + boff + (size_t)h * W_ * 64 + cb;
#pragma unroll
                for (int nt = 0; nt < 4; nt++) {
                    int px = p * 64 + nt * 16 + ln15;
                    u32 p0 = pack2(acc[hh][mt][nt][0] + bb[0], acc[hh][mt][nt][1] + bb[1]);
                    u32 p1 = pack2(acc[hh][mt][nt][2] + bb[2], acc[hh][mt][nt][3] + bb[3]);
                    *(u32*)(dst + (size_t)px * 64)     = p0;
                    *(u32*)(dst + (size_t)px * 64 + 2) = p1;
                }
            }
            // v: NCHW coalesced u16
#pragma unroll
            for (int r = 0; r < 4; r++) {
                u16* drow = v + boff + (size_t)(cb + r) * HW_ + (size_t)h * W_;
#pragma unroll
                for (int nt = 0; nt < 4; nt++) {
                    float vb_ = acc[hh][2][nt][r] + bvv[r];
                    drow[p * 64 + nt * 16 + ln15] = f2bf(vb_);
                    if (pass == 0) vhold[hh][nt][r] = vb_;
                }
            }
        }
        // pass 1: fused vT[c][w][h0..h0+3] write (one uint2 per (c,px))
        if (pass == 1) {
#pragma unroll
            for (int r = 0; r < 4; r++) {
                u16* vtc = vT + boff + (size_t)(cb + r) * HW_ + (size_t)h0;
#pragma unroll
                for (int nt = 0; nt < 4; nt++) {
                    int px = p * 64 + nt * 16 + ln15;
                    uint2 u;
                    u.x = pack2(vhold[0][nt][r], vhold[1][nt][r]);
                    u.y = pack2(acc[0][2][nt][r] + bvv[r], acc[1][2][nt][r] + bvv[r]);
                    *(uint2*)(vtc + (size_t)px * 128) = u;
                }
            }
        }
    }
}

// ---------------------------------------------------------------------------
// Column attention (flash pass 1). Block = (w, b). SWAPPED QK^T: S^T =
// mfma(K, Q) -> lane holds 32 g-values of ONE t-row. Row reduce = 31 reg-fmax
// + 2 shfl. P written to LDS as packed uint2 (16 stores vs 64).
// bounds(256,4): whole 1024-block grid co-resident. Ocol stored BF16.
// ---------------------------------------------------------------------------
__global__ __launch_bounds__(256, 4) void col_kernel(
    const u16* __restrict__ qN, const u16* __restrict__ kN,
    const u16* __restrict__ vT,
    float* __restrict__ maxH, float* __restrict__ sumH,
    u16* __restrict__ Ocol)
{
    const size_t boff = (size_t)blockIdx.z * CHW_;
    const size_t soff = (size_t)blockIdx.z * HW_;
    qN += boff; kN += boff; vT += boff; Ocol += boff;
    maxH += soff; sumH += soff;

    const int s    = blockIdx.x;               // w
    const int tid  = threadIdx.x;
    const int lane = tid & 63, wv = tid >> 6;
    const int ln15 = lane & 15, quad = lane >> 4;

    __shared__ __align__(16) u16 smemU[18432]; // 36864 B
    u16* Qs = smemU;                           // [128 t][72]
    u16* Ks = smemU + 9216;

#pragma unroll
    for (int it = 0; it < 4; it++) {
        int idx = tid + it * 256;
        int t = idx >> 3, cg = (idx & 7) * 8;
        size_t off = (size_t)t * 8192 + (size_t)s * 64 + cg;
        *(uint4*)(Qs + t * 72 + cg) = *(const uint4*)(qN + off);
        *(uint4*)(Ks + t * 72 + cg) = *(const uint4*)(kN + off);
    }
    __syncthreads();

    // swapped: A = K (M = g), B = Q (N = t)
    f32x4 Sc[2][8];                            // [tt][gt]
#pragma unroll
    for (int tt = 0; tt < 2; tt++)
#pragma unroll
        for (int gt = 0; gt < 8; gt++)
            Sc[tt][gt] = (f32x4){0.f, 0.f, 0.f, 0.f};

#pragma unroll
    for (int ks = 0; ks < 2; ks++) {
        bf16x8 bq_[2];
#pragma unroll
        for (int tt = 0; tt < 2; tt++)
            bq_[tt] = *(const bf16x8*)(Qs + ((wv * 2 + tt) * 16 + ln15) * 72 + ks * 32 + quad * 8);
#pragma unroll
        for (int gt = 0; gt < 8; gt++) {
            bf16x8 ak = *(const bf16x8*)(Ks + (gt * 16 + ln15) * 72 + ks * 32 + quad * 8);
#pragma unroll
            for (int tt = 0; tt < 2; tt++)
                Sc[tt][gt] = __builtin_amdgcn_mfma_f32_16x16x32_bf16(ak, bq_[tt], Sc[tt][gt], 0, 0, 0);
        }
    }

    const int tb[2] = { (wv * 2) * 16 + ln15, (wv * 2 + 1) * 16 + ln15 };
    // diag mask g == t
#pragma unroll
    for (int tt = 0; tt < 2; tt++)
#pragma unroll
        for (int gt = 0; gt < 8; gt++)
#pragma unroll
            for (int r = 0; r < 4; r++)
                if (gt * 16 + quad * 4 + r == tb[tt]) Sc[tt][gt][r] = -1e30f;

    // per-t stats: 31 reg-fmax + 2 shfl; cache e^{S-m} in Sc
#pragma unroll
    for (int tt = 0; tt < 2; tt++) {
        float m = Sc[tt][0][0];
#pragma unroll
        for (int gt = 0; gt < 8; gt++)
#pragma unroll
            for (int r = 0; r < 4; r++) m = fmaxf(m, Sc[tt][gt][r]);
        m = fmaxf(m, __shfl_xor(m, 16));
        m = fmaxf(m, __shfl_xor(m, 32));
        float ss = 0.f;
#pragma unroll
        for (int gt = 0; gt < 8; gt++)
#pragma unroll
            for (int r = 0; r < 4; r++) {
                float e = __expf(Sc[tt][gt][r] - m);
                ss += e;
                Sc[tt][gt][r] = e;
            }
        ss += __shfl_xor(ss, 16);
        ss += __shfl_xor(ss, 32);
        if (quad == 0) {
            int pix = tb[tt] * W_ + s;
            maxH[pix] = m; sumH[pix] = ss;
        }
    }
    __syncthreads();
    u16* Ps = smemU;                           // [128 t][136]
#pragma unroll
    for (int tt = 0; tt < 2; tt++)
#pragma unroll
        for (int gt = 0; gt < 8; gt++) {
            u32 lo = pack2(Sc[tt][gt][0], Sc[tt][gt][1]);
            u32 hi = pack2(Sc[tt][gt][2], Sc[tt][gt][3]);
            *(uint2*)(Ps + tb[tt] * 136 + gt * 16 + quad * 4) = make_uint2(lo, hi);
        }
    __syncthreads();

    f32x4 Oc[2][4];
#pragma unroll
    for (int mt = 0; mt < 2; mt++)
#pragma unroll
        for (int nt = 0; nt < 4; nt++)
            Oc[mt][nt] = (f32x4){0.f, 0.f, 0.f, 0.f};
#pragma unroll
    for (int kg = 0; kg < 4; kg++) {
        bf16x8 ap[2];
#pragma unroll
        for (int mt = 0; mt < 2; mt++)
            ap[mt] = *(const bf16x8*)(Ps + (wv * 32 + mt * 16 + ln15) * 136 + kg * 32 + quad * 8);
#pragma unroll
        for (int nt = 0; nt < 4; nt++) {
            bf16x8 bv_ = *(const bf16x8*)(vT + (size_t)(nt * 16 + ln15) * HW_ + (size_t)s * 128 + kg * 32 + quad * 8);
#pragma unroll
            for (int mt = 0; mt < 2; mt++)
                Oc[mt][nt] = __builtin_amdgcn_mfma_f32_16x16x32_bf16(ap[mt], bv_, Oc[mt][nt], 0, 0, 0);
        }
    }
    __syncthreads();
    u16* OfU = smemU;                          // [128 t][72] bf16
#pragma unroll
    for (int mt = 0; mt < 2; mt++)
#pragma unroll
        for (int nt = 0; nt < 4; nt++)
#pragma unroll
            for (int r = 0; r < 4; r++)
                OfU[(wv * 32 + mt * 16 + quad * 4 + r) * 72 + nt * 16 + ln15] = f2bf(Oc[mt][nt][r]);
    __syncthreads();
#pragma unroll
    for (int it = 0; it < 4; it++) {
        int idx = tid + it * 256;              // 0..1023
        int t = idx >> 3, c8 = (idx & 7) * 8;
        *(uint4*)(Ocol + ((size_t)t * 128 + s) * 64 + c8) = *(uint4*)(OfU + t * 72 + c8);
    }
}

// ---------------------------------------------------------------------------
// Row attention (flash pass 2 + epilogue). Block = (h, b). SWAPPED QK^T
// (no mask); per-t merge with col stats (2 shfl); alpha via LDS tail;
// P packed uint2; Ocol read BF16. bounds(256,4): whole grid co-resident.
// ---------------------------------------------------------------------------
__global__ __launch_bounds__(256, 4) void row_kernel(
    const u16* __restrict__ qN, const u16* __restrict__ kN,
    const u16* __restrict__ v,
    const float* __restrict__ x, const float* __restrict__ gammap,
    const float* __restrict__ maxH, const float* __restrict__ sumH,
    const u16* __restrict__ Ocol, float* __restrict__ out)
{
    const size_t boff = (size_t)blockIdx.z * CHW_;
    const size_t soff = (size_t)blockIdx.z * HW_;
    qN += boff; kN += boff; v += boff; Ocol += boff; x += boff; out += boff;
    maxH += soff; sumH += soff;

    const int s    = blockIdx.x;               // h
    const int tid  = threadIdx.x;
    const int lane = tid & 63, wv = tid >> 6;
    const int ln15 = lane & 15, quad = lane >> 4;

    __shared__ __align__(16) u16 smemU[18432]; // 36864 B
    u16* Qs = smemU;
    u16* Ks = smemU + 9216;
    float* alL = (float*)(smemU + 17408);      // byte 34816: float[128] alpha

    const int tb[2] = { (wv * 2) * 16 + ln15, (wv * 2 + 1) * 16 + ln15 };
    // prefetch col stats for lane's own 2 t values
    float mcv[2], scv[2];
#pragma unroll
    for (int tt = 0; tt < 2; tt++) {
        mcv[tt] = maxH[s * W_ + tb[tt]];
        scv[tt] = sumH[s * W_ + tb[tt]];
    }

#pragma unroll
    for (int it = 0; it < 4; it++) {
        int idx = tid + it * 256;
        int t = idx >> 3, cg = (idx & 7) * 8;
        size_t off = (size_t)s * 8192 + (size_t)t * 64 + cg;
        *(uint4*)(Qs + t * 72 + cg) = *(const uint4*)(qN + off);
        *(uint4*)(Ks + t * 72 + cg) = *(const uint4*)(kN + off);
    }
    __syncthreads();

    f32x4 Sc[2][8];                            // [tt][gt]
#pragma unroll
    for (int tt = 0; tt < 2; tt++)
#pragma unroll
        for (int gt = 0; gt < 8; gt++)
            Sc[tt][gt] = (f32x4){0.f, 0.f, 0.f, 0.f};
#pragma unroll
    for (int ks = 0; ks < 2; ks++) {
        bf16x8 bq_[2];
#pragma unroll
        for (int tt = 0; tt < 2; tt++)
            bq_[tt] = *(const bf16x8*)(Qs + ((wv * 2 + tt) * 16 + ln15) * 72 + ks * 32 + quad * 8);
#pragma unroll
        for (int gt = 0; gt < 8; gt++) {
            bf16x8 ak = *(const bf16x8*)(Ks + (gt * 16 + ln15) * 72 + ks * 32 + quad * 8);
#pragma unroll
            for (int tt = 0; tt < 2; tt++)
                Sc[tt][gt] = __builtin_amdgcn_mfma_f32_16x16x32_bf16(ak, bq_[tt], Sc[tt][gt], 0, 0, 0);
        }
    }

    // per-t stats + merge with col stats
    float be[2];
#pragma unroll
    for (int tt = 0; tt < 2; tt++) {
        float m = Sc[tt][0][0];
#pragma unroll
        for (int gt = 0; gt < 8; gt++)
#pragma unroll
            for (int r = 0; r < 4; r++) m = fmaxf(m, Sc[tt][gt][r]);
        m = fmaxf(m, __shfl_xor(m, 16));
        m = fmaxf(m, __shfl_xor(m, 32));
        float ss = 0.f;
#pragma unroll
        for (int gt = 0; gt < 8; gt++)
#pragma unroll
            for (int r = 0; r < 4; r++) {
                float e = __expf(Sc[tt][gt][r] - m);
                ss += e;
                Sc[tt][gt][r] = e;
            }
        ss += __shfl_xor(ss, 16);
        ss += __shfl_xor(ss, 32);
        float mc = sanit(mcv[tt], -3e38f, 3e38f);
        float sc = sanit(scv[tt], 0.f, 3e38f);
        float mm = fmaxf(mc, m);
        float dd = sc * __expf(fminf(mc - mm, 0.f)) + ss * __expf(m - mm);
        float rv = 1.0f / fmaxf(dd, 1e-30f);
        be[tt] = __expf(m - mm) * rv;          // m <= mm always
        if (quad == 0) alL[tb[tt]] = __expf(fminf(mc - mm, 0.f)) * rv;
    }
    __syncthreads();
    u16* Ps = smemU;                           // [128 t][136]
#pragma unroll
    for (int tt = 0; tt < 2; tt++)
#pragma unroll
        for (int gt = 0; gt < 8; gt++) {
            u32 lo = pack2(Sc[tt][gt][0] * be[tt], Sc[tt][gt][1] * be[tt]);
            u32 hi = pack2(Sc[tt][gt][2] * be[tt], Sc[tt][gt][3] * be[tt]);
            *(uint2*)(Ps + tb[tt] * 136 + gt * 16 + quad * 4) = make_uint2(lo, hi);
        }
    __syncthreads();

    f32x4 Oc[2][4];
#pragma unroll
    for (int mt = 0; mt < 2; mt++)
#pragma unroll
        for (int nt = 0; nt < 4; nt++)
            Oc[mt][nt] = (f32x4){0.f, 0.f, 0.f, 0.f};
#pragma unroll
    for (int kg = 0; kg < 4; kg++) {
        bf16x8 ap[2];
#pragma unroll
        for (int mt = 0; mt < 2; mt++)
            ap[mt] = *(const bf16x8*)(Ps + (wv * 32 + mt * 16 + ln15) * 136 + kg * 32 + quad * 8);
#pragma unroll
        for (int nt = 0; nt < 4; nt++) {
            bf16x8 bv_ = *(const bf16x8*)(v + (size_t)(nt * 16 + ln15) * HW_ + (size_t)s * 128 + kg * 32 + quad * 8);
#pragma unroll
            for (int mt = 0; mt < 2; mt++)
                Oc[mt][nt] = __builtin_amdgcn_mfma_f32_16x16x32_bf16(ap[mt], bv_, Oc[mt][nt], 0, 0, 0);
        }
    }
    __syncthreads();

    const float gmm = gammap[0];
    float* Of = (float*)smemU;                 // [64 c][132 w] (33792 B < alL offset)
#pragma unroll
    for (int mt = 0; mt < 2; mt++)
#pragma unroll
        for (int nt = 0; nt < 4; nt++) {
            float fv[4];
            int c = nt * 16 + ln15;
#pragma unroll
            for (int r = 0; r < 4; r++) {
                int tt = wv * 32 + mt * 16 + quad * 4 + r;
                float oc = bf2f(Ocol[((size_t)s * 128 + tt) * 64 + c]);
                fv[r] = gmm * (Oc[mt][nt][r] + alL[tt] * oc);
            }
            int w0 = wv * 32 + mt * 16 + quad * 4;
            *(float4*)(Of + c * 132 + w0) = make_float4(fv[0], fv[1], fv[2], fv[3]);
        }
    __syncthreads();
    int c = tid >> 2, w0 = (tid & 3) * 32;
#pragma unroll
    for (int i = 0; i < 8; i++) {
        int w = w0 + i * 4;
        float4 xo = *(const float4*)(x + (size_t)c * HW_ + (size_t)s * 128 + w);
        float4 of = *(const float4*)(Of + c * 132 + w);
        *(float4*)(out + (size_t)c * HW_ + (size_t)s * 128 + w) =
            make_float4(of.x + xo.x, of.y + xo.y, of.z + xo.z, of.w + xo.w);
    }
}

// ---------------------------------------------------------------------------
// ws: qN|kN|v|vT (bf16, nb*2MB each) + Ocol region (nb*4MB, bf16 uses half)
// + maxH,sumH (nb*64KB each) + Wt 216KB. Fallback 2-pass.
// xb (bf16, nb*2.08MB) ALIASES Ocol region (dead before col writes Ocol).
// vt_kernel removed: conv writes vT directly (fused).
// ---------------------------------------------------------------------------
extern "C" void kernel_launch(void* const* d_in, const int* in_sizes, int n_in,
                              void* d_out, int out_size, void* d_ws, size_t ws_size,
                              hipStream_t stream)
{
    const float* x  = (const float*)d_in[0];
    const float* Wq = (const float*)d_in[1];
    const float* bq = (const float*)d_in[2];
    const float* Wk = (const float*)d_in[3];
    const float* bk = (const float*)d_in[4];
    const float* Wv = (const float*)d_in[5];
    const float* bv = (const float*)d_in[6];
    const float* gm = (const float*)d_in[7];
    float* out = (float*)d_out;

    char* ws = (char*)d_ws;
    const size_t need1 = 4 * (size_t)B_ * CHW_ * 2 + (size_t)B_ * CHW_ * 4
                       + 2 * (size_t)B_ * HW_ * 4 + 221184;
    int passes = (ws_size >= need1) ? 1 : 2;
    int nb = B_ / passes;

    const size_t SL = (size_t)nb * CHW_ * 2;
    const size_t OC = (size_t)nb * CHW_ * 4;
    const size_t ST = (size_t)nb * HW_ * 4;
    u16*   qNb  = (u16*)(ws);
    u16*   kNb  = (u16*)(ws + SL);
    u16*   v    = (u16*)(ws + 2 * SL);
    u16*   vT   = (u16*)(ws + 3 * SL);
    u16*   Ocol = (u16*)(ws + 4 * SL);        // bf16, uses half of OC region
    float* maxH = (float*)(ws + 4 * SL + OC);
    float* sumH = (float*)(ws + 4 * SL + OC + ST);
    u16*   Wt   = (u16*)(ws + 4 * SL + OC + 2 * ST);
    u16*   xb   = (u16*)Ocol;   // alias: xb dead before col writes Ocol

    dim3 blk(256);
    prep_weights<<<dim3(9, 48), blk, 0, stream>>>(Wq, Wk, Wv, Wt);

    for (int p = 0; p < passes; p++) {
        const float* xbp = x + (size_t)p * nb * CHW_;
        float* ob = out + (size_t)p * nb * CHW_;
        xprep_kernel<<<dim3(130, nb), blk, 0, stream>>>(xbp, xb);
        conv_mfma_kernel<<<dim3(64, nb), blk, 0, stream>>>(xb, Wt, bq, bk, bv, qNb, kNb, v, vT);
        col_kernel<<<dim3(W_, 1, nb), blk, 0, stream>>>(qNb, kNb, vT, maxH, sumH, Ocol);
        row_kernel<<<dim3(H_, 1, nb), blk, 0, stream>>>(qNb, kNb, v, xbp, gm, maxH, sumH, Ocol, ob);
    }
}

// Round 12
// 186.674 us; speedup vs baseline: 1.0764x; 1.0764x over previous
//
#include <hip/hip_runtime.h>
#include <hip/hip_bf16.h>

#define B_ 8
#define C_ 64
#define H_ 128
#define W_ 128
#define HW_  ((size_t)H_ * W_)          // 16384
#define CHW_ ((size_t)C_ * H_ * W_)     // 1048576

typedef unsigned short u16;
typedef unsigned int   u32;
typedef __attribute__((ext_vector_type(8))) short bf16x8;
typedef __attribute__((ext_vector_type(4))) float f32x4;

__device__ __forceinline__ float bf2f(u16 h) {
    union { u32 u; float f; } c; c.u = ((u32)h) << 16; return c.f;
}
__device__ __forceinline__ u16 f2bf(float f) {
    union { float f; u32 u; } c; c.f = f;
    u32 u = c.u;
    u32 r = (u + 0x7fffu + ((u >> 16) & 1u)) >> 16;
    return (u16)r;
}
__device__ __forceinline__ u32 pack2(float a, float b) {
    return (u32)f2bf(a) | ((u32)f2bf(b) << 16);
}
__device__ __forceinline__ float sanit(float x, float lo, float hi) {
    return fminf(fmaxf(x, lo), hi);   // NaN-killing clamp
}
// async global->LDS, 16B per lane, LDS dest = uniform base + lane*16
__device__ __forceinline__ void gload_lds16(const u16* g, u16* l) {
    __builtin_amdgcn_global_load_lds(
        (const __attribute__((address_space(1))) void*)g,
        (__attribute__((address_space(3))) void*)l, 16, 0, 0);
}

// ---------------------------------------------------------------------------
// Weight prep: Wt[tap][cog(192)][ci(64)] bf16, cog = {q:0..63, k:64..127, v:128..191}
// ---------------------------------------------------------------------------
__global__ __launch_bounds__(256) void prep_weights(
    const float* __restrict__ Wq, const float* __restrict__ Wk,
    const float* __restrict__ Wv, u16* __restrict__ Wt)
{
    int tap = blockIdx.x;
    int cog = blockIdx.y * 4 + (threadIdx.x >> 6);
    int ci  = threadIdx.x & 63;
    int arr = cog >> 6, co = cog & 63;
    const float* src = arr == 0 ? Wq : (arr == 1 ? Wk : Wv);
    Wt[tap * 12288 + cog * 64 + ci] = f2bf(src[(co * 64 + ci) * 9 + tap]);
}

// ---------------------------------------------------------------------------
// x prep: fp32 NCHW -> bf16 [b][h'(130)][g(8)][px(128)][8ch], rows h'=0 and
// h'=129 zeroed (h-halo). One thread builds one 16B unit (8 ch of one px).
// grid (130, nb), 256 thr.
// ---------------------------------------------------------------------------
__global__ __launch_bounds__(256) void xprep_kernel(
    const float* __restrict__ x, u16* __restrict__ xb)
{
    const int hp  = blockIdx.x;            // 0..129
    const int tid = threadIdx.x;
    u16* dst = xb + ((size_t)blockIdx.y * 130 + hp) * 8192;
    if (hp == 0 || hp == 129) {
#pragma unroll
        for (int i = 0; i < 4; i++)
            *(uint4*)(dst + (size_t)(tid + i * 256) * 8) = (uint4){0, 0, 0, 0};
        return;
    }
    const float* xr = x + (size_t)blockIdx.y * CHW_ + (size_t)(hp - 1) * W_;
#pragma unroll
    for (int it = 0; it < 4; it++) {
        int idx = tid + it * 256;          // 0..1023
        int px  = idx & 127;
        int g   = idx >> 7;                // 0..7
        float vb[8];
#pragma unroll
        for (int e = 0; e < 8; e++)
            vb[e] = xr[(size_t)(g * 8 + e) * HW_ + px];
        uint4 o;
        o.x = pack2(vb[0], vb[1]);
        o.y = pack2(vb[2], vb[3]);
        o.z = pack2(vb[4], vb[5]);
        o.w = pack2(vb[6], vb[7]);
        *(uint4*)(dst + (size_t)(g * 128 + px) * 8) = o;
    }
}

// ---------------------------------------------------------------------------
// Conv implicit-GEMM MFMA, 4-row/half-px blocks (R10-proven). grid (64, nb)
// XCD-swizzled, 4 waves. Block (p, hq, b): 192 ch x 64 px x 4 h rows; stages
// 6 halo rows x 68 px once (52 KB); two h-pair passes (acc 96 AGPR, weights
// double-buffered per pass). Epilogue register->global.
// LDS: xI[6 row][8 g][68 px][8 ch] = 52224 B.
// ---------------------------------------------------------------------------
__global__ __launch_bounds__(256, 2) void conv_mfma_kernel(
    const u16* __restrict__ xb, const u16* __restrict__ Wt,
    const float* __restrict__ bq, const float* __restrict__ bk,
    const float* __restrict__ bv,
    u16* __restrict__ qN, u16* __restrict__ kN, u16* __restrict__ v)
{
    // bijective XCD swizzle: nwg = 64*nb, divisible by 8
    const int nwg  = gridDim.x * gridDim.y;
    const int flat = blockIdx.y * gridDim.x + blockIdx.x;
    const int wg   = (flat & 7) * (nwg >> 3) + (flat >> 3);
    const int p    = wg & 1;                   // px half
    const int hq   = (wg >> 1) & 31;           // h quad
    const int bidx = wg >> 6;
    const int h0   = hq * 4;
    const size_t boff = (size_t)bidx * CHW_;
    const int tid  = threadIdx.x;
    const int lane = tid & 63, wv = tid >> 6;
    const int ln15 = lane & 15, quad = lane >> 4;

    __shared__ __align__(16) u16 xI[26112];    // 52224 B

    // per-lane weight-fragment offset: + mt*4096 + ks*32 + tap*12288
    const int woff = (wv * 16 + ln15) * 64 + quad * 8;

    // stage 6 rows x 8 g, 1088 B each as two overlapping full-wave 1KB chunks
    const u16* xrow0 = xb + ((size_t)bidx * 130 + h0) * 8192;  // xb row h0+i
#pragma unroll
    for (int it = 0; it < 12; it++) {
        int unit = wv * 12 + it;               // 0..47
        int i = unit >> 3, g = unit & 7;
        const u16* src = xrow0 + (size_t)i * 8192 + g * 1024 + p * 512 - 16;
        u16* dst = xI + (i * 8 + g) * 544;
        gload_lds16(src + lane * 8, dst);           // bytes [0,1024)
        gload_lds16(src + 32 + lane * 8, dst + 32); // bytes [64,1088)
    }
    __syncthreads();
    // zero the w-boundary column: global px -1 (p=0) / 128 (p=1)
    if (tid < 48) {
        int i = tid >> 3, g = tid & 7;
        int slot = p ? 66 : 1;
        *(uint4*)(xI + (i * 8 + g) * 544 + slot * 8) = (uint4){0, 0, 0, 0};
    }
    __syncthreads();

    const int cb = wv * 16 + quad * 4;
    float bqv[4], bkv[4], bvv[4];
#pragma unroll
    for (int r = 0; r < 4; r++) {
        bqv[r] = bq[cb + r]; bkv[r] = bk[cb + r]; bvv[r] = bv[cb + r];
    }

#pragma unroll
    for (int pass = 0; pass < 2; pass++) {
        f32x4 acc[2][3][4];
#pragma unroll
        for (int hh = 0; hh < 2; hh++)
#pragma unroll
            for (int mt = 0; mt < 3; mt++)
#pragma unroll
                for (int nt = 0; nt < 4; nt++)
                    acc[hh][mt][nt] = (f32x4){0.f, 0.f, 0.f, 0.f};

        bf16x8 wcur[2][3], wnxt[2][3];
#pragma unroll
        for (int ks = 0; ks < 2; ks++)
#pragma unroll
            for (int mt = 0; mt < 3; mt++)
                wcur[ks][mt] = *(const bf16x8*)(Wt + woff + mt * 4096 + ks * 32);

#pragma unroll
        for (int tap = 0; tap < 9; tap++) {
            const int dh = tap / 3, dw = tap % 3;
            if (tap < 8) {
#pragma unroll
                for (int ks = 0; ks < 2; ks++)
#pragma unroll
                    for (int mt = 0; mt < 3; mt++)
                        wnxt[ks][mt] = *(const bf16x8*)(Wt + (tap + 1) * 12288 + woff + mt * 4096 + ks * 32);
            }
#pragma unroll
            for (int hh = 0; hh < 2; hh++) {
                const int row = pass * 2 + hh + dh;      // 0..5
#pragma unroll
                for (int ks = 0; ks < 2; ks++) {
                    bf16x8 bfr[4];
#pragma unroll
                    for (int nt = 0; nt < 4; nt++)
                        bfr[nt] = *(const bf16x8*)(xI + (row * 8 + quad + ks * 4) * 544
                                                      + (nt * 16 + ln15 + 1 + dw) * 8);
                    __builtin_amdgcn_s_setprio(1);
#pragma unroll
                    for (int mt = 0; mt < 3; mt++)
#pragma unroll
                        for (int nt = 0; nt < 4; nt++)
                            acc[hh][mt][nt] = __builtin_amdgcn_mfma_f32_16x16x32_bf16(
                                wcur[ks][mt], bfr[nt], acc[hh][mt][nt], 0, 0, 0);
                    __builtin_amdgcn_s_setprio(0);
                }
            }
            if (tap < 8) {
#pragma unroll
                for (int ks = 0; ks < 2; ks++)
#pragma unroll
                    for (int mt = 0; mt < 3; mt++)
                        wcur[ks][mt] = wnxt[ks][mt];
            }
        }

        // epilogue for this pass's two rows
#pragma unroll
        for (int hh = 0; hh < 2; hh++) {
            const int h = h0 + pass * 2 + hh;
            // q/k: NHWC packed u32 direct
#pragma unroll
            for (int mt = 0; mt < 2; mt++) {
                const float* bb = mt == 0 ? bqv : bkv;
                u16* dst = (mt ? kN : qN) + boff + (size_t)h * W_ * 64 + cb;
#pragma unroll
                for (int nt = 0; nt < 4; nt++) {
                    int px = p * 64 + nt * 16 + ln15;
                    u32 p0 = pack2(acc[hh][mt][nt][0] + bb[0], acc[hh][mt][nt][1] + bb[1]);
                    u32 p1 = pack2(acc[hh][mt][nt][2] + bb[2], acc[hh][mt][nt][3] + bb[3]);
                    *(u32*)(dst + (size_t)px * 64)     = p0;
                    *(u32*)(dst + (size_t)px * 64 + 2) = p1;
                }
            }
            // v: NCHW coalesced u16
#pragma unroll
            for (int r = 0; r < 4; r++) {
                u16* drow = v + boff + (size_t)(cb + r) * HW_ + (size_t)h * W_;
#pragma unroll
                for (int nt = 0; nt < 4; nt++)
                    drow[p * 64 + nt * 16 + ln15] = f2bf(acc[hh][2][nt][r] + bvv[r]);
            }
        }
    }
}

// ---------------------------------------------------------------------------
// vT: [c][h][w] -> [c][w][h] (64x64 tiles). grid (4, C, nb).
// ---------------------------------------------------------------------------
__global__ __launch_bounds__(256) void vt_kernel(
    const u16* __restrict__ v, u16* __restrict__ vT)
{
    __shared__ u16 Ts[64 * 72];
    const u16* src = v  + (size_t)blockIdx.z * CHW_ + (size_t)blockIdx.y * HW_;
    u16* dst       = vT + (size_t)blockIdx.z * CHW_ + (size_t)blockIdx.y * HW_;
    const int ti = blockIdx.x & 1, tj = blockIdx.x >> 1;
    const int r0 = ti * 64, c0 = tj * 64;
    const int tid = threadIdx.x;
    const int r = tid >> 2, cq = tid & 3;
#pragma unroll
    for (int i = 0; i < 2; i++) {
        uint4 u = *(const uint4*)(src + (size_t)(r0 + r) * 128 + c0 + cq * 16 + i * 8);
        *(uint4*)(Ts + r * 72 + cq * 16 + i * 8) = u;
    }
    __syncthreads();
    const int wr = tid >> 2, hq = tid & 3;
    union { u16 o[16]; uint4 v4[2]; } t;
#pragma unroll
    for (int j = 0; j < 16; j++) t.o[j] = Ts[(hq * 16 + j) * 72 + wr];
    *(uint4*)(dst + (size_t)(c0 + wr) * 128 + r0 + hq * 16)     = t.v4[0];
    *(uint4*)(dst + (size_t)(c0 + wr) * 128 + r0 + hq * 16 + 8) = t.v4[1];
}

// ---------------------------------------------------------------------------
// Column attention (flash pass 1). Block = (w, b). SWAPPED QK^T: S^T =
// mfma(K, Q) -> lane holds 32 g-values of ONE t-row. Row reduce = 31 reg-fmax
// + 2 shfl. Stats stored as ONE float2 (m, sum) per pixel. P packed uint2.
// bounds(256,4): whole 1024-block grid co-resident. Ocol stored BF16.
// ---------------------------------------------------------------------------
__global__ __launch_bounds__(256, 4) void col_kernel(
    const u16* __restrict__ qN, const u16* __restrict__ kN,
    const u16* __restrict__ vT,
    float2* __restrict__ msl,
    u16* __restrict__ Ocol)
{
    const size_t boff = (size_t)blockIdx.z * CHW_;
    const size_t soff = (size_t)blockIdx.z * HW_;
    qN += boff; kN += boff; vT += boff; Ocol += boff;
    msl += soff;

    const int s    = blockIdx.x;               // w
    const int tid  = threadIdx.x;
    const int lane = tid & 63, wv = tid >> 6;
    const int ln15 = lane & 15, quad = lane >> 4;

    __shared__ __align__(16) u16 smemU[18432]; // 36864 B
    u16* Qs = smemU;                           // [128 t][72]
    u16* Ks = smemU + 9216;

#pragma unroll
    for (int it = 0; it < 4; it++) {
        int idx = tid + it * 256;
        int t = idx >> 3, cg = (idx & 7) * 8;
        size_t off = (size_t)t * 8192 + (size_t)s * 64 + cg;
        *(uint4*)(Qs + t * 72 + cg) = *(const uint4*)(qN + off);
        *(uint4*)(Ks + t * 72 + cg) = *(const uint4*)(kN + off);
    }
    __syncthreads();

    // swapped: A = K (M = g), B = Q (N = t)
    f32x4 Sc[2][8];                            // [tt][gt]
#pragma unroll
    for (int tt = 0; tt < 2; tt++)
#pragma unroll
        for (int gt = 0; gt < 8; gt++)
            Sc[tt][gt] = (f32x4){0.f, 0.f, 0.f, 0.f};

#pragma unroll
    for (int ks = 0; ks < 2; ks++) {
        bf16x8 bq_[2];
#pragma unroll
        for (int tt = 0; tt < 2; tt++)
            bq_[tt] = *(const bf16x8*)(Qs + ((wv * 2 + tt) * 16 + ln15) * 72 + ks * 32 + quad * 8);
#pragma unroll
        for (int gt = 0; gt < 8; gt++) {
            bf16x8 ak = *(const bf16x8*)(Ks + (gt * 16 + ln15) * 72 + ks * 32 + quad * 8);
#pragma unroll
            for (int tt = 0; tt < 2; tt++)
                Sc[tt][gt] = __builtin_amdgcn_mfma_f32_16x16x32_bf16(ak, bq_[tt], Sc[tt][gt], 0, 0, 0);
        }
    }

    const int tb[2] = { (wv * 2) * 16 + ln15, (wv * 2 + 1) * 16 + ln15 };
    // diag mask g == t
#pragma unroll
    for (int tt = 0; tt < 2; tt++)
#pragma unroll
        for (int gt = 0; gt < 8; gt++)
#pragma unroll
            for (int r = 0; r < 4; r++)
                if (gt * 16 + quad * 4 + r == tb[tt]) Sc[tt][gt][r] = -1e30f;

    // per-t stats: 31 reg-fmax + 2 shfl; cache e^{S-m} in Sc
#pragma unroll
    for (int tt = 0; tt < 2; tt++) {
        float m = Sc[tt][0][0];
#pragma unroll
        for (int gt = 0; gt < 8; gt++)
#pragma unroll
            for (int r = 0; r < 4; r++) m = fmaxf(m, Sc[tt][gt][r]);
        m = fmaxf(m, __shfl_xor(m, 16));
        m = fmaxf(m, __shfl_xor(m, 32));
        float ss = 0.f;
#pragma unroll
        for (int gt = 0; gt < 8; gt++)
#pragma unroll
            for (int r = 0; r < 4; r++) {
                float e = __expf(Sc[tt][gt][r] - m);
                ss += e;
                Sc[tt][gt][r] = e;
            }
        ss += __shfl_xor(ss, 16);
        ss += __shfl_xor(ss, 32);
        if (quad == 0)
            msl[tb[tt] * W_ + s] = make_float2(m, ss);
    }
    __syncthreads();
    u16* Ps = smemU;                           // [128 t][136]
#pragma unroll
    for (int tt = 0; tt < 2; tt++)
#pragma unroll
        for (int gt = 0; gt < 8; gt++) {
            u32 lo = pack2(Sc[tt][gt][0], Sc[tt][gt][1]);
            u32 hi = pack2(Sc[tt][gt][2], Sc[tt][gt][3]);
            *(uint2*)(Ps + tb[tt] * 136 + gt * 16 + quad * 4) = make_uint2(lo, hi);
        }
    __syncthreads();

    f32x4 Oc[2][4];
#pragma unroll
    for (int mt = 0; mt < 2; mt++)
#pragma unroll
        for (int nt = 0; nt < 4; nt++)
            Oc[mt][nt] = (f32x4){0.f, 0.f, 0.f, 0.f};
#pragma unroll
    for (int kg = 0; kg < 4; kg++) {
        bf16x8 ap[2];
#pragma unroll
        for (int mt = 0; mt < 2; mt++)
            ap[mt] = *(const bf16x8*)(Ps + (wv * 32 + mt * 16 + ln15) * 136 + kg * 32 + quad * 8);
#pragma unroll
        for (int nt = 0; nt < 4; nt++) {
            bf16x8 bv_ = *(const bf16x8*)(vT + (size_t)(nt * 16 + ln15) * HW_ + (size_t)s * 128 + kg * 32 + quad * 8);
#pragma unroll
            for (int mt = 0; mt < 2; mt++)
                Oc[mt][nt] = __builtin_amdgcn_mfma_f32_16x16x32_bf16(ap[mt], bv_, Oc[mt][nt], 0, 0, 0);
        }
    }
    __syncthreads();
    u16* OfU = smemU;                          // [128 t][72] bf16
#pragma unroll
    for (int mt = 0; mt < 2; mt++)
#pragma unroll
        for (int nt = 0; nt < 4; nt++)
#pragma unroll
            for (int r = 0; r < 4; r++)
                OfU[(wv * 32 + mt * 16 + quad * 4 + r) * 72 + nt * 16 + ln15] = f2bf(Oc[mt][nt][r]);
    __syncthreads();
#pragma unroll
    for (int it = 0; it < 4; it++) {
        int idx = tid + it * 256;              // 0..1023
        int t = idx >> 3, c8 = (idx & 7) * 8;
        *(uint4*)(Ocol + ((size_t)t * 128 + s) * 64 + c8) = *(uint4*)(OfU + t * 72 + c8);
    }
}

// ---------------------------------------------------------------------------
// Row attention (flash pass 2 + epilogue). Block = (h, b). SWAPPED QK^T
// (no mask); per-t merge with col stats (one float2 load, 2 shfl); alpha via
// LDS tail; P packed uint2; Ocol read BF16. bounds(256,4) co-resident.
// ---------------------------------------------------------------------------
__global__ __launch_bounds__(256, 4) void row_kernel(
    const u16* __restrict__ qN, const u16* __restrict__ kN,
    const u16* __restrict__ v,
    const float* __restrict__ x, const float* __restrict__ gammap,
    const float2* __restrict__ msl,
    const u16* __restrict__ Ocol, float* __restrict__ out)
{
    const size_t boff = (size_t)blockIdx.z * CHW_;
    const size_t soff = (size_t)blockIdx.z * HW_;
    qN += boff; kN += boff; v += boff; Ocol += boff; x += boff; out += boff;
    msl += soff;

    const int s    = blockIdx.x;               // h
    const int tid  = threadIdx.x;
    const int lane = tid & 63, wv = tid >> 6;
    const int ln15 = lane & 15, quad = lane >> 4;

    __shared__ __align__(16) u16 smemU[18432]; // 36864 B
    u16* Qs = smemU;
    u16* Ks = smemU + 9216;
    float* alL = (float*)(smemU + 17408);      // byte 34816: float[128] alpha

    const int tb[2] = { (wv * 2) * 16 + ln15, (wv * 2 + 1) * 16 + ln15 };
    // prefetch col stats for lane's own 2 t values (single 8B load each)
    float2 mslv[2];
#pragma unroll
    for (int tt = 0; tt < 2; tt++)
        mslv[tt] = msl[s * W_ + tb[tt]];

#pragma unroll
    for (int it = 0; it < 4; it++) {
        int idx = tid + it * 256;
        int t = idx >> 3, cg = (idx & 7) * 8;
        size_t off = (size_t)s * 8192 + (size_t)t * 64 + cg;
        *(uint4*)(Qs + t * 72 + cg) = *(const uint4*)(qN + off);
        *(uint4*)(Ks + t * 72 + cg) = *(const uint4*)(kN + off);
    }
    __syncthreads();

    f32x4 Sc[2][8];                            // [tt][gt]
#pragma unroll
    for (int tt = 0; tt < 2; tt++)
#pragma unroll
        for (int gt = 0; gt < 8; gt++)
            Sc[tt][gt] = (f32x4){0.f, 0.f, 0.f, 0.f};
#pragma unroll
    for (int ks = 0; ks < 2; ks++) {
        bf16x8 bq_[2];
#pragma unroll
        for (int tt = 0; tt < 2; tt++)
            bq_[tt] = *(const bf16x8*)(Qs + ((wv * 2 + tt) * 16 + ln15) * 72 + ks * 32 + quad * 8);
#pragma unroll
        for (int gt = 0; gt < 8; gt++) {
            bf16x8 ak = *(const bf16x8*)(Ks + (gt * 16 + ln15) * 72 + ks * 32 + quad * 8);
#pragma unroll
            for (int tt = 0; tt < 2; tt++)
                Sc[tt][gt] = __builtin_amdgcn_mfma_f32_16x16x32_bf16(ak, bq_[tt], Sc[tt][gt], 0, 0, 0);
        }
    }

    // per-t stats + merge with col stats
    float be[2];
#pragma unroll
    for (int tt = 0; tt < 2; tt++) {
        float m = Sc[tt][0][0];
#pragma unroll
        for (int gt = 0; gt < 8; gt++)
#pragma unroll
            for (int r = 0; r < 4; r++) m = fmaxf(m, Sc[tt][gt][r]);
        m = fmaxf(m, __shfl_xor(m, 16));
        m = fmaxf(m, __shfl_xor(m, 32));
        float ss = 0.f;
#pragma unroll
        for (int gt = 0; gt < 8; gt++)
#pragma unroll
            for (int r = 0; r < 4; r++) {
                float e = __expf(Sc[tt][gt][r] - m);
                ss += e;
                Sc[tt][gt][r] = e;
            }
        ss += __shfl_xor(ss, 16);
        ss += __shfl_xor(ss, 32);
        float mc = sanit(mslv[tt].x, -3e38f, 3e38f);
        float sc = sanit(mslv[tt].y, 0.f, 3e38f);
        float mm = fmaxf(mc, m);
        float dd = sc * __expf(fminf(mc - mm, 0.f)) + ss * __expf(m - mm);
        float rv = 1.0f / fmaxf(dd, 1e-30f);
        be[tt] = __expf(m - mm) * rv;          // m <= mm always
        if (quad == 0) alL[tb[tt]] = __expf(fminf(mc - mm, 0.f)) * rv;
    }
    __syncthreads();
    u16* Ps = smemU;                           // [128 t][136]
#pragma unroll
    for (int tt = 0; tt < 2; tt++)
#pragma unroll
        for (int gt = 0; gt < 8; gt++) {
            u32 lo = pack2(Sc[tt][gt][0] * be[tt], Sc[tt][gt][1] * be[tt]);
            u32 hi = pack2(Sc[tt][gt][2] * be[tt], Sc[tt][gt][3] * be[tt]);
            *(uint2*)(Ps + tb[tt] * 136 + gt * 16 + quad * 4) = make_uint2(lo, hi);
        }
    __syncthreads();

    f32x4 Oc[2][4];
#pragma unroll
    for (int mt = 0; mt < 2; mt++)
#pragma unroll
        for (int nt = 0; nt < 4; nt++)
            Oc[mt][nt] = (f32x4){0.f, 0.f, 0.f, 0.f};
#pragma unroll
    for (int kg = 0; kg < 4; kg++) {
        bf16x8 ap[2];
#pragma unroll
        for (int mt = 0; mt < 2; mt++)
            ap[mt] = *(const bf16x8*)(Ps + (wv * 32 + mt * 16 + ln15) * 136 + kg * 32 + quad * 8);
#pragma unroll
        for (int nt = 0; nt < 4; nt++) {
            bf16x8 bv_ = *(const bf16x8*)(v + (size_t)(nt * 16 + ln15) * HW_ + (size_t)s * 128 + kg * 32 + quad * 8);
#pragma unroll
            for (int mt = 0; mt < 2; mt++)
                Oc[mt][nt] = __builtin_amdgcn_mfma_f32_16x16x32_bf16(ap[mt], bv_, Oc[mt][nt], 0, 0, 0);
        }
    }
    __syncthreads();

    const float gmm = gammap[0];
    float* Of = (float*)smemU;                 // [64 c][132 w] (33792 B < alL offset)
#pragma unroll
    for (int mt = 0; mt < 2; mt++)
#pragma unroll
        for (int nt = 0; nt < 4; nt++) {
            float fv[4];
            int c = nt * 16 + ln15;
#pragma unroll
            for (int r = 0; r < 4; r++) {
                int tt = wv * 32 + mt * 16 + quad * 4 + r;
                float oc = bf2f(Ocol[((size_t)s * 128 + tt) * 64 + c]);
                fv[r] = gmm * (Oc[mt][nt][r] + alL[tt] * oc);
            }
            int w0 = wv * 32 + mt * 16 + quad * 4;
            *(float4*)(Of + c * 132 + w0) = make_float4(fv[0], fv[1], fv[2], fv[3]);
        }
    __syncthreads();
    int c = tid >> 2, w0 = (tid & 3) * 32;
#pragma unroll
    for (int i = 0; i < 8; i++) {
        int w = w0 + i * 4;
        float4 xo = *(const float4*)(x + (size_t)c * HW_ + (size_t)s * 128 + w);
        float4 of = *(const float4*)(Of + c * 132 + w);
        *(float4*)(out + (size_t)c * HW_ + (size_t)s * 128 + w) =
            make_float4(of.x + xo.x, of.y + xo.y, of.z + xo.z, of.w + xo.w);
    }
}

// ---------------------------------------------------------------------------
// ws: qN|kN|v|vT (bf16, nb*2MB each) + Ocol region (nb*4MB, bf16 uses half)
// + msl (float2, nb*128KB) + Wt 216KB. Fallback 2-pass.
// xb (bf16, nb*2.08MB) ALIASES Ocol region (dead before col writes Ocol).
// ---------------------------------------------------------------------------
extern "C" void kernel_launch(void* const* d_in, const int* in_sizes, int n_in,
                              void* d_out, int out_size, void* d_ws, size_t ws_size,
                              hipStream_t stream)
{
    const float* x  = (const float*)d_in[0];
    const float* Wq = (const float*)d_in[1];
    const float* bq = (const float*)d_in[2];
    const float* Wk = (const float*)d_in[3];
    const float* bk = (const float*)d_in[4];
    const float* Wv = (const float*)d_in[5];
    const float* bv = (const float*)d_in[6];
    const float* gm = (const float*)d_in[7];
    float* out = (float*)d_out;

    char* ws = (char*)d_ws;
    const size_t need1 = 4 * (size_t)B_ * CHW_ * 2 + (size_t)B_ * CHW_ * 4
                       + 2 * (size_t)B_ * HW_ * 4 + 221184;
    int passes = (ws_size >= need1) ? 1 : 2;
    int nb = B_ / passes;

    const size_t SL = (size_t)nb * CHW_ * 2;
    const size_t OC = (size_t)nb * CHW_ * 4;
    const size_t ST = (size_t)nb * HW_ * 8;   // float2 stats
    u16*    qNb  = (u16*)(ws);
    u16*    kNb  = (u16*)(ws + SL);
    u16*    v    = (u16*)(ws + 2 * SL);
    u16*    vT   = (u16*)(ws + 3 * SL);
    u16*    Ocol = (u16*)(ws + 4 * SL);       // bf16, uses half of OC region
    float2* msl  = (float2*)(ws + 4 * SL + OC);
    u16*    Wt   = (u16*)(ws + 4 * SL + OC + ST);
    u16*    xb   = (u16*)Ocol;   // alias: xb dead before col writes Ocol

    dim3 blk(256);
    prep_weights<<<dim3(9, 48), blk, 0, stream>>>(Wq, Wk, Wv, Wt);

    for (int p = 0; p < passes; p++) {
        const float* xbp = x + (size_t)p * nb * CHW_;
        float* ob = out + (size_t)p * nb * CHW_;
        xprep_kernel<<<dim3(130, nb), blk, 0, stream>>>(xbp, xb);
        conv_mfma_kernel<<<dim3(64, nb), blk, 0, stream>>>(xb, Wt, bq, bk, bv, qNb, kNb, v);
        vt_kernel<<<dim3(4, C_, nb), blk, 0, stream>>>(v, vT);
        col_kernel<<<dim3(W_, 1, nb), blk, 0, stream>>>(qNb, kNb, vT, msl, Ocol);
        row_kernel<<<dim3(H_, 1, nb), blk, 0, stream>>>(qNb, kNb, v, xbp, gm, msl, Ocol, ob);
    }
}